// Round 1
// baseline (296.856 us; speedup 1.0000x reference)
//
#include <hip/hip_runtime.h>
#include <hip/hip_bf16.h>

typedef __attribute__((ext_vector_type(8))) short bf16x8;
typedef __attribute__((ext_vector_type(4))) float f32x4;

constexpr int Bn = 4, Hn = 16, S = 2048, D = 64;
constexpr int BQ = 128;   // q rows per block
constexpr int TKV = 64;   // kv tile size
constexpr float LOG2E = 1.44269504088896340736f;

__device__ __forceinline__ short f2bf(float f) {
    union { float f; unsigned u; } v; v.f = f;
    unsigned r = v.u + 0x7fffu + ((v.u >> 16) & 1u);
    return (short)(r >> 16);
}

__device__ __forceinline__ f32x4 vmax4(f32x4 a, f32x4 b) {
    f32x4 r;
    r[0] = fmaxf(a[0], b[0]); r[1] = fmaxf(a[1], b[1]);
    r[2] = fmaxf(a[2], b[2]); r[3] = fmaxf(a[3], b[3]);
    return r;
}

__global__ __launch_bounds__(256, 2) void attn_fwd(
    const float* __restrict__ Qg, const float* __restrict__ Kg,
    const float* __restrict__ Vg, const void* __restrict__ maskg,
    float* __restrict__ outg)
{
    __shared__ alignas(16) short Kt[64][72];   // [key][d]
    __shared__ alignas(16) short Vt[64][72];   // transposed [dv][key]
    __shared__ alignas(16) short Pt[128][72];  // [q_local][key]
    __shared__ float bias[S];

    const int blk = blockIdx.x;
    const int qt  = blk & 15;          // S/BQ = 16 q-tiles
    const int bh  = blk >> 4;          // 0..63
    const int b   = bh >> 4;           // H = 16
    const int q0  = qt * BQ;

    const float* Qp = Qg + ((size_t)bh * S + q0) * D;
    const float* Kp = Kg + (size_t)bh * S * D;
    const float* Vp = Vg + (size_t)bh * S * D;
    float*       Op = outg + ((size_t)bh * S + q0) * D;

    const int t  = threadIdx.x;
    const int w  = t >> 6;
    const int l  = t & 63;
    const int lr = l & 15;
    const int lg = l >> 4;

    // ---- mask dtype sniff (bool-bytes vs int32) + bias staging ----
    {
        const unsigned* mu = (const unsigned*)maskg;
        bool is_bytes = false;
        #pragma unroll 8
        for (int i = 0; i < 64; ++i) is_bytes |= (mu[i] > 1u);
        if (is_bytes) {
            const unsigned char* mb = (const unsigned char*)maskg + (size_t)b * S;
            for (int i = t; i < S; i += 256) bias[i] = mb[i] ? -1e9f : 0.0f;
        } else {
            const int* mi = (const int*)maskg + (size_t)b * S;
            for (int i = t; i < S; i += 256) bias[i] = mi[i] ? -1e9f : 0.0f;
        }
    }

    // ---- Q fragments, scaled by log2e/8 (log2-units softmax) ----
    const float qscale = 0.125f * LOG2E;
    bf16x8 qf[2][2];
    #pragma unroll
    for (int rt = 0; rt < 2; ++rt) {
        const int row = w * 32 + rt * 16 + lr;
        #pragma unroll
        for (int g = 0; g < 2; ++g) {
            const float* src = Qp + row * D + g * 32 + lg * 8;
            bf16x8 f;
            #pragma unroll
            for (int i = 0; i < 8; ++i) f[i] = f2bf(src[i] * qscale);
            qf[rt][g] = f;
        }
    }

    f32x4 Oacc[2][4];
    #pragma unroll
    for (int rt = 0; rt < 2; ++rt)
        #pragma unroll
        for (int d = 0; d < 4; ++d) Oacc[rt][d] = f32x4{0.f, 0.f, 0.f, 0.f};
    f32x4 mrun[2], lrun[2];
    mrun[0] = mrun[1] = f32x4{-1e30f, -1e30f, -1e30f, -1e30f};
    lrun[0] = lrun[1] = f32x4{0.f, 0.f, 0.f, 0.f};

    const float CD2 = (2.0f / ((float)S * (float)S)) * LOG2E;

    for (int kv = 0; kv < S; kv += TKV) {
        __syncthreads();   // previous tile's LDS reads complete
        // ---- stage K tile [64 keys][64 d] as bf16 ----
        {
            const int key = t >> 3;           // 0..31
            const int dc  = (t & 7) * 8;
            #pragma unroll
            for (int it = 0; it < 2; ++it) {
                const float* src = Kp + (size_t)(kv + key + it * 32) * D + dc;
                bf16x8 f;
                #pragma unroll
                for (int i = 0; i < 8; ++i) f[i] = f2bf(src[i]);
                *(bf16x8*)&Kt[key + it * 32][dc] = f;
            }
        }
        // ---- stage V tile transposed [dv][key] as bf16 ----
        {
            const int dv = t & 63;
            const int kb = (t >> 6) * 16;
            bf16x8 tmp2[2];
            #pragma unroll
            for (int i = 0; i < 16; ++i)
                tmp2[i >> 3][i & 7] = f2bf(Vp[(size_t)(kv + kb + i) * D + dv]);
            *(bf16x8*)&Vt[dv][kb]     = tmp2[0];
            *(bf16x8*)&Vt[dv][kb + 8] = tmp2[1];
        }
        __syncthreads();

        // ---- QK^T: wave computes its 32 q-rows x 64 keys ----
        bf16x8 kf[4][2];
        #pragma unroll
        for (int kt = 0; kt < 4; ++kt)
            #pragma unroll
            for (int g = 0; g < 2; ++g)
                kf[kt][g] = *(const bf16x8*)&Kt[kt * 16 + lr][g * 32 + lg * 8];

        f32x4 sc[2][4];
        #pragma unroll
        for (int rt = 0; rt < 2; ++rt)
            #pragma unroll
            for (int kt = 0; kt < 4; ++kt) {
                f32x4 acc = f32x4{0.f, 0.f, 0.f, 0.f};
                acc = __builtin_amdgcn_mfma_f32_16x16x32_bf16(qf[rt][0], kf[kt][0], acc, 0, 0, 0);
                acc = __builtin_amdgcn_mfma_f32_16x16x32_bf16(qf[rt][1], kf[kt][1], acc, 0, 0, 0);
                sc[rt][kt] = acc;
            }

        // ---- mask bias ----
        float bb[4];
        #pragma unroll
        for (int kt = 0; kt < 4; ++kt) bb[kt] = bias[kv + kt * 16 + lr];
        #pragma unroll
        for (int rt = 0; rt < 2; ++rt)
            #pragma unroll
            for (int kt = 0; kt < 4; ++kt)
                sc[rt][kt] += bb[kt];

        // ---- online softmax (log2 units), decay folded into PV exponent ----
        #pragma unroll
        for (int rt = 0; rt < 2; ++rt) {
            f32x4 mt = vmax4(vmax4(sc[rt][0], sc[rt][1]), vmax4(sc[rt][2], sc[rt][3]));
            #pragma unroll
            for (int j = 0; j < 4; ++j) {
                float v = mt[j];
                v = fmaxf(v, __shfl_xor(v, 1, 64));
                v = fmaxf(v, __shfl_xor(v, 2, 64));
                v = fmaxf(v, __shfl_xor(v, 4, 64));
                v = fmaxf(v, __shfl_xor(v, 8, 64));
                mt[j] = v;
            }
            f32x4 mnew = vmax4(mrun[rt], mt);
            f32x4 resc;
            #pragma unroll
            for (int j = 0; j < 4; ++j) resc[j] = exp2f(mrun[rt][j] - mnew[j]);
            mrun[rt] = mnew;
            lrun[rt] *= resc;
            #pragma unroll
            for (int d = 0; d < 4; ++d) Oacc[rt][d] *= resc;

            f32x4 lpart = f32x4{0.f, 0.f, 0.f, 0.f};
            const int qrow_base = q0 + w * 32 + rt * 16 + lg * 4;  // + j
            #pragma unroll
            for (int kt = 0; kt < 4; ++kt) {
                const int kk = kv + kt * 16 + lr;
                #pragma unroll
                for (int j = 0; j < 4; ++j) {
                    const float s = sc[rt][kt][j];
                    const float p = exp2f(s - mnew[j]);
                    lpart[j] += p;
                    const float r = (float)(qrow_base + j - kk);
                    const float pd = exp2f(s - mnew[j] - CD2 * r * r);
                    Pt[w * 32 + rt * 16 + lg * 4 + j][kt * 16 + lr] = f2bf(pd);
                }
            }
            #pragma unroll
            for (int j = 0; j < 4; ++j) {
                float v = lpart[j];
                v += __shfl_xor(v, 1, 64);
                v += __shfl_xor(v, 2, 64);
                v += __shfl_xor(v, 4, 64);
                v += __shfl_xor(v, 8, 64);
                lrun[rt][j] += v;
            }
        }

        // P written/read by the SAME wave only: wave-local LDS fence suffices
        asm volatile("s_waitcnt lgkmcnt(0)" ::: "memory");
        __builtin_amdgcn_sched_barrier(0);

        // ---- PV ----
        bf16x8 vf[4][2];
        #pragma unroll
        for (int dt = 0; dt < 4; ++dt)
            #pragma unroll
            for (int g = 0; g < 2; ++g)
                vf[dt][g] = *(const bf16x8*)&Vt[dt * 16 + lr][g * 32 + lg * 8];

        #pragma unroll
        for (int rt = 0; rt < 2; ++rt) {
            bf16x8 pf[2];
            #pragma unroll
            for (int g = 0; g < 2; ++g)
                pf[g] = *(const bf16x8*)&Pt[w * 32 + rt * 16 + lr][g * 32 + lg * 8];
            #pragma unroll
            for (int dt = 0; dt < 4; ++dt) {
                Oacc[rt][dt] = __builtin_amdgcn_mfma_f32_16x16x32_bf16(pf[0], vf[dt][0], Oacc[rt][dt], 0, 0, 0);
                Oacc[rt][dt] = __builtin_amdgcn_mfma_f32_16x16x32_bf16(pf[1], vf[dt][1], Oacc[rt][dt], 0, 0, 0);
            }
        }
    }

    // ---- epilogue: O / l ----
    #pragma unroll
    for (int rt = 0; rt < 2; ++rt)
        #pragma unroll
        for (int j = 0; j < 4; ++j) {
            const float inv = 1.0f / lrun[rt][j];
            const int row = w * 32 + rt * 16 + lg * 4 + j;
            #pragma unroll
            for (int dt = 0; dt < 4; ++dt)
                Op[(size_t)row * D + dt * 16 + lr] = Oacc[rt][dt][j] * inv;
        }
}

extern "C" void kernel_launch(void* const* d_in, const int* in_sizes, int n_in,
                              void* d_out, int out_size, void* d_ws, size_t ws_size,
                              hipStream_t stream) {
    const float* Q = (const float*)d_in[0];
    const float* K = (const float*)d_in[1];
    const float* V = (const float*)d_in[2];
    const void*  M = d_in[3];
    float* out = (float*)d_out;
    const int nblk = Bn * Hn * (S / BQ);   // 1024
    attn_fwd<<<dim3(nblk), dim3(256), 0, stream>>>(Q, K, V, M, out);
}

// Round 2
// 190.746 us; speedup vs baseline: 1.5563x; 1.5563x over previous
//
#include <hip/hip_runtime.h>
#include <hip/hip_bf16.h>

typedef __attribute__((ext_vector_type(8))) short bf16x8;
typedef __attribute__((ext_vector_type(4))) float f32x4;
typedef __attribute__((ext_vector_type(4))) unsigned u32x4;

constexpr int Bn = 4, Hn = 16, S = 2048, D = 64;
constexpr int BQ = 128;   // q rows per block
constexpr int TKV = 64;   // kv tile size
constexpr float LOG2E = 1.44269504088896340736f;

__device__ __forceinline__ unsigned cvtpk(float lo, float hi) {
    unsigned r;
    asm("v_cvt_pk_bf16_f32 %0, %1, %2" : "=v"(r) : "v"(lo), "v"(hi));
    return r;
}

__global__ __launch_bounds__(256, 3) void attn_fwd(
    const float* __restrict__ Qg, const float* __restrict__ Kg,
    const float* __restrict__ Vg, const void* __restrict__ maskg,
    float* __restrict__ outg)
{
    __shared__ alignas(16) short Kt[64][72];   // [key][d]
    __shared__ alignas(16) short Vt[64][72];   // transposed [dv][key]
    __shared__ alignas(16) float biass[S];
    __shared__ alignas(16) float dtab[2176];   // decay, 4-key granularity, mid -1.5 baked in

    const int blk = blockIdx.x;
    const int qt  = blk & 15;          // S/BQ = 16 q-tiles
    const int bh  = blk >> 4;          // 0..63
    const int b   = bh >> 4;           // H = 16
    const int q0  = qt * BQ;

    const float* Qp = Qg + ((size_t)bh * S + q0) * D;
    const float* Kp = Kg + (size_t)bh * S * D;
    const float* Vp = Vg + (size_t)bh * S * D;
    float*       Op = outg + ((size_t)bh * S + q0) * D;

    const int t  = threadIdx.x;
    const int w  = t >> 6;
    const int l  = t & 63;
    const int lr = l & 15;
    const int lg = l >> 4;

    // ---- mask dtype sniff (bool-bytes vs int32) + bias staging ----
    {
        const unsigned* mu = (const unsigned*)maskg;
        bool is_bytes = false;
        #pragma unroll 8
        for (int i = 0; i < 64; ++i) is_bytes |= (mu[i] > 1u);
        if (is_bytes) {
            const unsigned char* mb = (const unsigned char*)maskg + (size_t)b * S;
            for (int i = t; i < S; i += 256) biass[i] = mb[i] ? -1e9f : 0.0f;
        } else {
            const int* mi = (const int*)maskg + (size_t)b * S;
            for (int i = t; i < S; i += 256) biass[i] = mi[i] ? -1e9f : 0.0f;
        }
    }
    // ---- per-block decay table: dtab[i] = 2^(-CD2*(i+q0-2048.5)^2), i = qrow_local - key + 2047 ----
    const float CD2 = (2.0f / ((float)S * (float)S)) * LOG2E;
    for (int i = t; i < 2176; i += 256) {
        const float r = (float)(i + q0) - 2048.5f;
        dtab[i] = __builtin_exp2f(-CD2 * r * r);
    }

    // ---- Q fragments (B-operand), scaled by log2e/8 ----
    const float qscale = 0.125f * LOG2E;
    bf16x8 qf[2][2];
    #pragma unroll
    for (int rt = 0; rt < 2; ++rt) {
        const int row = w * 32 + rt * 16 + lr;
        #pragma unroll
        for (int g = 0; g < 2; ++g) {
            const float* src = Qp + row * D + g * 32 + lg * 8;
            union { unsigned u[4]; bf16x8 v; } cv;
            #pragma unroll
            for (int jj = 0; jj < 4; ++jj)
                cv.u[jj] = cvtpk(src[2 * jj] * qscale, src[2 * jj + 1] * qscale);
            qf[rt][g] = cv.v;
        }
    }

    f32x4 Oacc[2][4];   // [rt][dt]: col=lane&15 = q-row(lr), row = dv = dt*16+lg*4+j
    #pragma unroll
    for (int rt = 0; rt < 2; ++rt)
        #pragma unroll
        for (int dt = 0; dt < 4; ++dt) Oacc[rt][dt] = f32x4{0.f, 0.f, 0.f, 0.f};
    float mrun[2] = {-1e30f, -1e30f};
    float lrun[2] = {0.f, 0.f};   // per-lane PARTIAL row-sums (reduced at epilogue)

    const int ib0 = w * 32 + lr + 2047 - lg * 4;        // + rt*16 - kv - kt*16 at use
    const int addr_w0 = (lr + ((l & 16) << 1)) * 4;     // (lr + 32*bit4)*4
    const int addr_w1 = addr_w0 + 64;                   // +16 lanes
    const bool b5 = (l & 32) != 0;

    for (int kv = 0; kv < S; kv += TKV) {
        __syncthreads();   // previous tile's LDS reads complete
        // ---- stage K tile [64 keys][64 d] as bf16 ----
        {
            const int key = t >> 3;           // 0..31
            const int dc  = (t & 7) * 8;
            #pragma unroll
            for (int it = 0; it < 2; ++it) {
                const float* src = Kp + (size_t)(kv + key + it * 32) * D + dc;
                u32x4 pk;
                #pragma unroll
                for (int jj = 0; jj < 4; ++jj)
                    pk[jj] = cvtpk(src[2 * jj], src[2 * jj + 1]);
                *(u32x4*)&Kt[key + it * 32][dc] = pk;
            }
        }
        // ---- stage V tile transposed [dv][key] as bf16 ----
        {
            const int dv = t & 63;
            const int kb = (t >> 6) * 16;
            float f[16];
            #pragma unroll
            for (int i = 0; i < 16; ++i) f[i] = Vp[(size_t)(kv + kb + i) * D + dv];
            u32x4 p0, p1;
            #pragma unroll
            for (int jj = 0; jj < 4; ++jj) {
                p0[jj] = cvtpk(f[2 * jj], f[2 * jj + 1]);
                p1[jj] = cvtpk(f[8 + 2 * jj], f[9 + 2 * jj]);
            }
            *(u32x4*)&Vt[dv][kb]     = p0;
            *(u32x4*)&Vt[dv][kb + 8] = p1;
        }
        __syncthreads();

        // ---- K fragments (A-operand) ----
        bf16x8 kf[4][2];
        #pragma unroll
        for (int kt = 0; kt < 4; ++kt)
            #pragma unroll
            for (int g = 0; g < 2; ++g)
                kf[kt][g] = *(const bf16x8*)&Kt[kt * 16 + lr][g * 32 + lg * 8];

        unsigned pa32[2][2][4];   // [rt][g][v] P^T B-fragment words

        #pragma unroll
        for (int rt = 0; rt < 2; ++rt) {
            // swapped QK^T: C[key][q], col = q = lr, row = key = kt*16+lg*4+j
            // mask bias folded in via C-operand init
            f32x4 sc[4];
            #pragma unroll
            for (int kt = 0; kt < 4; ++kt) {
                f32x4 acc = *(const f32x4*)&biass[kv + kt * 16 + lg * 4];
                acc = __builtin_amdgcn_mfma_f32_16x16x32_bf16(kf[kt][0], qf[rt][0], acc, 0, 0, 0);
                acc = __builtin_amdgcn_mfma_f32_16x16x32_bf16(kf[kt][1], qf[rt][1], acc, 0, 0, 0);
                sc[kt] = acc;
            }
            // in-register row max + 2 cross-lane folds
            float mt = fmaxf(fmaxf(sc[0][0], sc[0][1]), fmaxf(sc[0][2], sc[0][3]));
            #pragma unroll
            for (int kt = 1; kt < 4; ++kt)
                mt = fmaxf(mt, fmaxf(fmaxf(sc[kt][0], sc[kt][1]), fmaxf(sc[kt][2], sc[kt][3])));
            mt = fmaxf(mt, __shfl_xor(mt, 16, 64));
            mt = fmaxf(mt, __shfl_xor(mt, 32, 64));
            // defer-max (T13): skip rescale if max grew < 2^8
            if (!__all(mt <= mrun[rt] + 8.0f)) {
                const float mnew = fmaxf(mrun[rt], mt);
                const float rs = __builtin_exp2f(mrun[rt] - mnew);
                mrun[rt] = mnew;
                lrun[rt] *= rs;
                #pragma unroll
                for (int dt = 0; dt < 4; ++dt) Oacc[rt][dt] *= rs;
            }
            const float m  = mrun[rt];
            const int   ib = ib0 + rt * 16 - kv;
            float lp = 0.f;
            unsigned X[4][2];
            #pragma unroll
            for (int kt = 0; kt < 4; ++kt) {
                const float dk = dtab[ib - kt * 16];
                const float p0 = __builtin_exp2f(sc[kt][0] - m);
                const float p1 = __builtin_exp2f(sc[kt][1] - m);
                const float p2 = __builtin_exp2f(sc[kt][2] - m);
                const float p3 = __builtin_exp2f(sc[kt][3] - m);
                lp += (p0 + p1) + (p2 + p3);
                X[kt][0] = cvtpk(p0 * dk, p1 * dk);
                X[kt][1] = cvtpk(p2 * dk, p3 * dk);
            }
            lrun[rt] += lp;
            // ---- exchange: build P^T B-fragment (keys lg*8+i for q=lr) ----
            // word v=(w<<1)|u: register X[2g + destbit5][u], from lane (lr, bit4=w, bit5=destbit4)
            #pragma unroll
            for (int g = 0; g < 2; ++g)
                #pragma unroll
                for (int u = 0; u < 2; ++u) {
                    const int x0 = (int)X[2 * g][u], x1 = (int)X[2 * g + 1][u];
                    const int a0 = __builtin_amdgcn_ds_bpermute(addr_w0, x0);
                    const int a1 = __builtin_amdgcn_ds_bpermute(addr_w0, x1);
                    const int c0 = __builtin_amdgcn_ds_bpermute(addr_w1, x0);
                    const int c1 = __builtin_amdgcn_ds_bpermute(addr_w1, x1);
                    pa32[rt][g][u]     = (unsigned)(b5 ? a1 : a0);
                    pa32[rt][g][2 + u] = (unsigned)(b5 ? c1 : c0);
                }
        }

        // ---- PV (transposed): O^T = V^T · P^T, col = q = lr ----
        bf16x8 paf[2][2];
        #pragma unroll
        for (int rt = 0; rt < 2; ++rt)
            #pragma unroll
            for (int g = 0; g < 2; ++g) {
                union { unsigned u[4]; bf16x8 v; } cv;
                cv.u[0] = pa32[rt][g][0]; cv.u[1] = pa32[rt][g][1];
                cv.u[2] = pa32[rt][g][2]; cv.u[3] = pa32[rt][g][3];
                paf[rt][g] = cv.v;
            }
        #pragma unroll
        for (int dt = 0; dt < 4; ++dt) {
            const bf16x8 v0 = *(const bf16x8*)&Vt[dt * 16 + lr][lg * 8];
            const bf16x8 v1 = *(const bf16x8*)&Vt[dt * 16 + lr][32 + lg * 8];
            #pragma unroll
            for (int rt = 0; rt < 2; ++rt) {
                Oacc[rt][dt] = __builtin_amdgcn_mfma_f32_16x16x32_bf16(v0, paf[rt][0], Oacc[rt][dt], 0, 0, 0);
                Oacc[rt][dt] = __builtin_amdgcn_mfma_f32_16x16x32_bf16(v1, paf[rt][1], Oacc[rt][dt], 0, 0, 0);
            }
        }
    }

    // ---- epilogue: reduce partial l across lane-groups, O / l, vectorized store ----
    #pragma unroll
    for (int rt = 0; rt < 2; ++rt) {
        float ls = lrun[rt];
        ls += __shfl_xor(ls, 16, 64);
        ls += __shfl_xor(ls, 32, 64);
        const float inv = 1.0f / ls;
        const int row = w * 32 + rt * 16 + lr;
        #pragma unroll
        for (int dt = 0; dt < 4; ++dt) {
            f32x4 o = Oacc[rt][dt];
            o[0] *= inv; o[1] *= inv; o[2] *= inv; o[3] *= inv;
            *(f32x4*)&Op[(size_t)row * D + dt * 16 + lg * 4] = o;
        }
    }
}

extern "C" void kernel_launch(void* const* d_in, const int* in_sizes, int n_in,
                              void* d_out, int out_size, void* d_ws, size_t ws_size,
                              hipStream_t stream) {
    const float* Q = (const float*)d_in[0];
    const float* K = (const float*)d_in[1];
    const float* V = (const float*)d_in[2];
    const void*  M = d_in[3];
    float* out = (float*)d_out;
    const int nblk = Bn * Hn * (S / BQ);   // 1024
    attn_fwd<<<dim3(nblk), dim3(256), 0, stream>>>(Q, K, V, M, out);
}

// Round 3
// 136.450 us; speedup vs baseline: 2.1756x; 1.3979x over previous
//
#include <hip/hip_runtime.h>
#include <hip/hip_bf16.h>

typedef __attribute__((ext_vector_type(8))) short bf16x8;
typedef __attribute__((ext_vector_type(4))) short bf16x4;
typedef __attribute__((ext_vector_type(4))) float f32x4;
typedef __attribute__((ext_vector_type(4))) unsigned u32x4;
typedef __attribute__((ext_vector_type(4))) int i32x4;

constexpr int Bn = 4, Hn = 16, S = 2048, D = 64;
constexpr int BQ = 128;   // q rows per block
constexpr float LOG2E = 1.44269504088896340736f;

__device__ __forceinline__ unsigned cvtpk(float lo, float hi) {
    unsigned r;
    asm("v_cvt_pk_bf16_f32 %0, %1, %2" : "=v"(r) : "v"(lo), "v"(hi));
    return r;
}

__device__ __forceinline__ f32x4 mfma16(bf16x4 a, bf16x4 b, f32x4 c) {
#if __has_builtin(__builtin_amdgcn_mfma_f32_16x16x16bf16_1k)
    return __builtin_amdgcn_mfma_f32_16x16x16bf16_1k(a, b, c, 0, 0, 0);
#else
    asm volatile("v_mfma_f32_16x16x16_bf16 %0, %1, %2, %0"
                 : "+v"(c) : "v"(a), "v"(b));
    return c;
#endif
}

// ---------------- kernel 1: mask compaction (per batch) ----------------
__global__ void compact_mask(const void* __restrict__ maskg,
                             int* __restrict__ idxp, int* __restrict__ Mg) {
    const int b = blockIdx.x, t = threadIdx.x;
    __shared__ int wsum[4];
    __shared__ int Msh;

    // mask dtype sniff (bool-bytes vs int32)
    const unsigned* mu = (const unsigned*)maskg;
    bool is_bytes = false;
    #pragma unroll 8
    for (int i = 0; i < 64; ++i) is_bytes |= (mu[i] > 1u);

    int keep[8]; int cnt = 0;
    #pragma unroll
    for (int i = 0; i < 8; ++i) {
        const int key = t * 8 + i;
        int m;
        if (is_bytes) m = ((const unsigned char*)maskg)[b * S + key];
        else          m = ((const int*)maskg)[b * S + key];
        keep[i] = (m == 0);
        cnt += keep[i];
    }
    // wave inclusive scan
    const int l = t & 63, w = t >> 6;
    int pre = cnt;
    #pragma unroll
    for (int d = 1; d < 64; d <<= 1) {
        int v = __shfl_up(pre, d, 64);
        if (l >= d) pre += v;
    }
    if (l == 63) wsum[w] = pre;
    __syncthreads();
    int base = 0;
    for (int i = 0; i < w; ++i) base += wsum[i];
    int offs = base + pre - cnt;
    #pragma unroll
    for (int i = 0; i < 8; ++i)
        if (keep[i]) idxp[b * S + (offs++)] = t * 8 + i;
    if (t == 255) Msh = base + pre;
    __syncthreads();
    const int M = Msh;
    for (int i = M + t; i < S; i += 256) idxp[b * S + i] = 0;   // pad
    if (M == 0)   // degenerate: reference = uniform softmax; flag via sign
        for (int i = t; i < S; i += 256) idxp[b * S + i] = i;
    if (t == 0) Mg[b] = (M == 0) ? -1 : M;
}

// ---------------- kernel 2: attention over compacted keys ----------------
__global__ __launch_bounds__(256, 3) void attn_fwd(
    const float* __restrict__ Qg, const float* __restrict__ Kg,
    const float* __restrict__ Vg, const int* __restrict__ idxp,
    const int* __restrict__ Mg, float* __restrict__ outg)
{
    __shared__ alignas(16) short Kt[64][72];   // [ckey][d]
    __shared__ alignas(16) short Vt[64][72];   // transposed [dv][ckey]
    __shared__ alignas(16) float dtab[2176];   // exact decay vs (qrow-key)
    __shared__ alignas(16) int   idxs[64];     // original key index per ckey

    const int blk = blockIdx.x;
    const int qt  = blk & 15;
    const int bh  = blk >> 4;
    const int b   = bh >> 4;
    const int q0  = qt * BQ;

    const float* Qp = Qg + ((size_t)bh * S + q0) * D;
    const float* Kp = Kg + (size_t)bh * S * D;
    const float* Vp = Vg + (size_t)bh * S * D;
    float*       Op = outg + ((size_t)bh * S + q0) * D;
    const int*   idxb = idxp + b * S;

    const int t  = threadIdx.x;
    const int w  = t >> 6;
    const int l  = t & 63;
    const int lr = l & 15;
    const int lg = l >> 4;

    const int  Mraw    = Mg[b];
    const bool uniform = (Mraw < 0);
    const int  M       = uniform ? S : Mraw;

    // exact decay table: dtab[i] = 2^(-CD2*(q0 + i - 2047)^2), i = qrow_local - key + 2047
    const float CD2 = (2.0f / ((float)S * (float)S)) * LOG2E;
    for (int i = t; i < 2176; i += 256) {
        const float r = (float)(q0 + i - 2047);
        dtab[i] = __builtin_exp2f(-CD2 * r * r);
    }

    // Q fragments (B-operand), scaled; zeroed in uniform mode (scores=0 => uniform softmax)
    const float qscale = uniform ? 0.0f : 0.125f * LOG2E;
    bf16x8 qf[2][2];
    #pragma unroll
    for (int rt = 0; rt < 2; ++rt) {
        const int row = w * 32 + rt * 16 + lr;
        #pragma unroll
        for (int g = 0; g < 2; ++g) {
            const float* src = Qp + row * D + g * 32 + lg * 8;
            union { unsigned u[4]; bf16x8 v; } cv;
            #pragma unroll
            for (int jj = 0; jj < 4; ++jj)
                cv.u[jj] = cvtpk(src[2 * jj] * qscale, src[2 * jj + 1] * qscale);
            qf[rt][g] = cv.v;
        }
    }

    f32x4 Oacc[2][4];   // [rt][dt]: col = q = lr, row = dv = dt*16+lg*4+reg
    #pragma unroll
    for (int rt = 0; rt < 2; ++rt)
        #pragma unroll
        for (int dt = 0; dt < 4; ++dt) Oacc[rt][dt] = f32x4{0.f, 0.f, 0.f, 0.f};
    float mrun[2] = {-1e30f, -1e30f};
    float lrun[2] = {0.f, 0.f};

    const int qrl2047 = w * 32 + lr + 2047;   // + rt*16 at use

    for (int kv = 0; kv < M; kv += 64) {
        const int  rem  = M - kv;          // >0
        const bool last = (rem <= 64);
        __syncthreads();
        // ---- stage K tile (gather rows via idx) ----
        {
            const int key = t >> 3;
            const int dc  = (t & 7) * 8;
            #pragma unroll
            for (int it = 0; it < 2; ++it) {
                const int row = idxb[kv + key + it * 32];   // 8-lane broadcast
                const float* src = Kp + (size_t)row * D + dc;
                u32x4 pk;
                #pragma unroll
                for (int jj = 0; jj < 4; ++jj)
                    pk[jj] = cvtpk(src[2 * jj], src[2 * jj + 1]);
                *(u32x4*)&Kt[key + it * 32][dc] = pk;
            }
        }
        if (t < 64) idxs[t] = idxb[kv + t];
        // ---- stage V tile transposed (gather rows) ----
        {
            const int dv = t & 63;
            const int kb = (t >> 6) * 16;
            float f[16];
            #pragma unroll
            for (int i = 0; i < 16; ++i) {
                int row = idxb[kv + kb + i];
                row = __builtin_amdgcn_readfirstlane(row);   // wave-uniform
                f[i] = Vp[(size_t)row * D + dv];
            }
            u32x4 p0, p1;
            #pragma unroll
            for (int jj = 0; jj < 4; ++jj) {
                p0[jj] = cvtpk(f[2 * jj], f[2 * jj + 1]);
                p1[jj] = cvtpk(f[8 + 2 * jj], f[9 + 2 * jj]);
            }
            *(u32x4*)&Vt[dv][kb]     = p0;
            *(u32x4*)&Vt[dv][kb + 8] = p1;
        }
        __syncthreads();

        // ---- K fragments (A-operand) ----
        bf16x8 kf[4][2];
        #pragma unroll
        for (int kt = 0; kt < 4; ++kt)
            #pragma unroll
            for (int g = 0; g < 2; ++g)
                kf[kt][g] = *(const bf16x8*)&Kt[kt * 16 + lr][g * 32 + lg * 8];

        bf16x4 Xb[2][4];   // [rt][kt] P^T B-fragment for K=16 MFMA — no exchange needed

        #pragma unroll
        for (int rt = 0; rt < 2; ++rt) {
            // swapped QK^T: C[ckey][q], col=q=lr, row=ckey=kt*16+lg*4+j
            f32x4 sc[4];
            #pragma unroll
            for (int kt = 0; kt < 4; ++kt) {
                f32x4 acc = f32x4{0.f, 0.f, 0.f, 0.f};
                acc = __builtin_amdgcn_mfma_f32_16x16x32_bf16(kf[kt][0], qf[rt][0], acc, 0, 0, 0);
                acc = __builtin_amdgcn_mfma_f32_16x16x32_bf16(kf[kt][1], qf[rt][1], acc, 0, 0, 0);
                sc[kt] = acc;
            }
            float mt = fmaxf(fmaxf(sc[0][0], sc[0][1]), fmaxf(sc[0][2], sc[0][3]));
            #pragma unroll
            for (int kt = 1; kt < 4; ++kt)
                mt = fmaxf(mt, fmaxf(fmaxf(sc[kt][0], sc[kt][1]), fmaxf(sc[kt][2], sc[kt][3])));
            mt = fmaxf(mt, __shfl_xor(mt, 16, 64));
            mt = fmaxf(mt, __shfl_xor(mt, 32, 64));
            if (!__all(mt <= mrun[rt] + 8.0f)) {   // defer-max
                const float mnew = fmaxf(mrun[rt], mt);
                const float rs = __builtin_exp2f(mrun[rt] - mnew);
                mrun[rt] = mnew;
                lrun[rt] *= rs;
                #pragma unroll
                for (int dt = 0; dt < 4; ++dt) Oacc[rt][dt] *= rs;
            }
            const float m  = mrun[rt];
            const int   qi = qrl2047 + rt * 16;
            float lp = 0.f;
            #pragma unroll
            for (int kt = 0; kt < 4; ++kt) {
                const i32x4 iv = *(const i32x4*)&idxs[kt * 16 + lg * 4];
                float p0 = __builtin_exp2f(sc[kt][0] - m);
                float p1 = __builtin_exp2f(sc[kt][1] - m);
                float p2 = __builtin_exp2f(sc[kt][2] - m);
                float p3 = __builtin_exp2f(sc[kt][3] - m);
                if (last) {   // zero padded keys (wave-uniform branch)
                    const int ck = kt * 16 + lg * 4;
                    p0 = (ck + 0 < rem) ? p0 : 0.f;
                    p1 = (ck + 1 < rem) ? p1 : 0.f;
                    p2 = (ck + 2 < rem) ? p2 : 0.f;
                    p3 = (ck + 3 < rem) ? p3 : 0.f;
                }
                lp += (p0 + p1) + (p2 + p3);
                const float d0 = dtab[qi - iv[0]];
                const float d1 = dtab[qi - iv[1]];
                const float d2 = dtab[qi - iv[2]];
                const float d3 = dtab[qi - iv[3]];
                union { unsigned u[2]; bf16x4 v; } cx;
                cx.u[0] = cvtpk(p0 * d0, p1 * d1);
                cx.u[1] = cvtpk(p2 * d2, p3 * d3);
                Xb[rt][kt] = cx.v;
            }
            lrun[rt] += lp;
        }

        // ---- PV via K=16 MFMA: O^T += V^T · P^T, zero cross-lane exchange ----
        #pragma unroll
        for (int kt = 0; kt < 4; ++kt) {
            bf16x4 vA[4];
            #pragma unroll
            for (int dt = 0; dt < 4; ++dt)
                vA[dt] = *(const bf16x4*)&Vt[dt * 16 + lr][kt * 16 + lg * 4];
            #pragma unroll
            for (int dt = 0; dt < 4; ++dt) {
                Oacc[0][dt] = mfma16(vA[dt], Xb[0][kt], Oacc[0][dt]);
                Oacc[1][dt] = mfma16(vA[dt], Xb[1][kt], Oacc[1][dt]);
            }
        }
    }

    // ---- epilogue ----
    #pragma unroll
    for (int rt = 0; rt < 2; ++rt) {
        float ls = lrun[rt];
        ls += __shfl_xor(ls, 16, 64);
        ls += __shfl_xor(ls, 32, 64);
        const float inv = 1.0f / ls;
        const int row = w * 32 + rt * 16 + lr;
        #pragma unroll
        for (int dt = 0; dt < 4; ++dt) {
            f32x4 o = Oacc[rt][dt];
            o[0] *= inv; o[1] *= inv; o[2] *= inv; o[3] *= inv;
            *(f32x4*)&Op[(size_t)row * D + dt * 16 + lg * 4] = o;
        }
    }
}

extern "C" void kernel_launch(void* const* d_in, const int* in_sizes, int n_in,
                              void* d_out, int out_size, void* d_ws, size_t ws_size,
                              hipStream_t stream) {
    const float* Q = (const float*)d_in[0];
    const float* K = (const float*)d_in[1];
    const float* V = (const float*)d_in[2];
    const void*  M = d_in[3];
    float* out = (float*)d_out;
    int* idxp = (int*)d_ws;            // 4*2048 ints
    int* Mg   = idxp + Bn * S;         // 4 ints   (total 32.8 KB << ws_size)
    compact_mask<<<dim3(Bn), dim3(256), 0, stream>>>(M, idxp, Mg);
    const int nblk = Bn * Hn * (S / BQ);   // 1024
    attn_fwd<<<dim3(nblk), dim3(256), 0, stream>>>(Q, K, V, idxp, Mg, out);
}